// Round 7
// baseline (616.674 us; speedup 1.0000x reference)
//
#include <hip/hip_runtime.h>
#include <stdint.h>

// Chebyshev GCN: out[b,n,o,t] = relu( sum_{k,c,m} cheb[k,m,n]*STDG[b,m,n]*x[b,m,c,t]*theta[k,c,o] )
// Per b:  C[n, j] = relu( sum_p A[p,n] * Y[p,j] ),  p=(k,m) in [0,3072), j=o*24+t
//   A[p,n] = cheb[k,m,n]*STDG[b,m,n]          (kprepA: bf16, stored [bb][n][p])
//   Y[p,j] = sum_c theta[k,c,o]*x[b,m,c,t]    (kprepY: bf16, written transposed [bb][j][p])
// Round-7 change (ONLY kgemm; kprepA/kprepY frozen validated):
//  - 256x256x64 8-phase-style schedule with counted vmcnt (T3+T4) + setprio (T5):
//    512 thr / 8 waves (2Mx4N), acc[8][4], LDS [buf2][kk2][256 rows][32 bf16] x (A,Y) = 128 KiB.
//    64B LDS rows make every ds_read_b128 fragment cover 16 rows x 64 B = 1024 contiguous
//    bytes exactly once -> conflict-free, linear global_load_lds dest (no swizzle needed).
//    4 phases per K-tile; stage half (operand,kk) of tile t+1 at phase p -> consumed 3-4
//    phases later; vmcnt(4) only at P2/P4 ends, never 0 in main loop. MFMA accumulation
//    order identical to validated r6 kernel -> expect bit-identical absmax 8.0.

#define BB   16
#define NN   1024
#define CIN  64
#define TT   24
#define KCH  3
#define COUT 64
#define PP   (KCH*NN)    // 3072 contraction length
#define JJ   (COUT*TT)   // 1536 output columns per n

typedef __attribute__((ext_vector_type(4))) float f32x4;
typedef __attribute__((ext_vector_type(8))) short bf16x8;

typedef __attribute__((address_space(1))) const unsigned int* gas_cuintp;
typedef __attribute__((address_space(3))) unsigned int* las_uintp;

static __device__ __forceinline__ unsigned short f2bf(float f){
  union { float f; unsigned u; } v; v.f = f;
  unsigned r = v.u + 0x7fffu + ((v.u >> 16) & 1u);   // round-to-nearest-even
  return (unsigned short)(r >> 16);
}

// ---------------- K0: A-prep  (masked = cheb*STDG, bf16, transpose to [bb][n][p]) ----------------
// [FROZEN r5/r6 validated] Grid (16 nt, 16 mt); chebT staged once; loop over b inside.
__global__ __launch_bounds__(256) void kprepA(const float* __restrict__ cheb,
                                              const float* __restrict__ stdg,
                                              unsigned short* __restrict__ Ah,
                                              int b0, int nb){
  int nt = blockIdx.x;
  int mt = blockIdx.y;
  __shared__ float ct[3][64][65];
  __shared__ float st[64][65];
  int tid = threadIdx.x;
  int rm = tid >> 2;
  int nc = (tid & 3) << 4;
  #pragma unroll
  for (int k = 0; k < 3; k++){
    const float* cp = cheb + ((size_t)(k*NN + mt*64 + rm))*NN + nt*64 + nc;
    #pragma unroll
    for (int i = 0; i < 16; i += 4){
      f32x4 cv = *(const f32x4*)(cp + i);
      #pragma unroll
      for (int q = 0; q < 4; q++) ct[k][nc + i + q][rm] = cv[q];
    }
  }
  int rn = tid >> 2;
  int mc = (tid & 3) << 4;
  for (int bb = 0; bb < nb; bb++){
    int b = b0 + bb;
    __syncthreads();
    const float* sp = stdg + ((size_t)(b*NN + mt*64 + rm))*NN + nt*64 + nc;
    #pragma unroll
    for (int i = 0; i < 16; i += 4){
      f32x4 sv = *(const f32x4*)(sp + i);
      #pragma unroll
      for (int q = 0; q < 4; q++) st[nc + i + q][rm] = sv[q];
    }
    __syncthreads();
    #pragma unroll
    for (int k = 0; k < 3; k++){
      union { unsigned short s[16]; uint4 v[2]; } hb;
      #pragma unroll
      for (int i = 0; i < 16; i++) hb.s[i] = f2bf(ct[k][rn][mc + i] * st[rn][mc + i]);
      size_t ob = ((size_t)(bb*NN + nt*64 + rn))*PP + (size_t)k*NN + mt*64 + mc;
      *(uint4*)(Ah + ob)     = hb.v[0];
      *(uint4*)(Ah + ob + 8) = hb.v[1];
    }
  }
}

// ---------------- K1: Y-prep fused with transpose -> writes [bb][j][p] ----------------
// [FROZEN r6 validated] T14 register prefetch of next c-chunk; ms on blockIdx.x (XCD pin).
__global__ __launch_bounds__(256) void kprepY(const float* __restrict__ x,
                                              const float* __restrict__ theta,
                                              unsigned short* __restrict__ Yt,
                                              int b0){
  int ms = blockIdx.x;
  int jb = blockIdx.y;
  int bb = blockIdx.z;
  int b  = b0 + bb;
  __shared__ float xs[32*196];
  __shared__ float ths[3*64*8];
  __shared__ unsigned short ytile[192*32];
  int tid = threadIdx.x;
  int mi = tid >> 3, oi = tid & 7;

  for (int i = tid; i < 3*64*8; i += 256){
    int k = i >> 9, rem = i & 511;
    int c = rem >> 3, o = rem & 7;
    ths[i] = theta[k*(CIN*COUT) + c*COUT + jb*8 + o];
  }

  float acc0[24], acc1[24], acc2[24];
  #pragma unroll
  for (int t = 0; t < 24; t++){ acc0[t]=0.f; acc1[t]=0.f; acc2[t]=0.f; }

  const f32x4* xg4 = (const f32x4*)(x + ((size_t)(b*NN + ms*32))*CIN*TT);

  int pm[6], pr[6];
  #pragma unroll
  for (int u = 0; u < 6; u++){
    int i4 = tid + u*256;
    pm[u] = i4 / 48; pr[u] = i4 - pm[u]*48;
  }
  f32x4 pf[6];
  #pragma unroll
  for (int u = 0; u < 6; u++) pf[u] = xg4[pm[u]*384 + pr[u]];

  for (int cc = 0; cc < 8; cc++){
    __syncthreads();
    #pragma unroll
    for (int u = 0; u < 6; u++) *(f32x4*)&xs[pm[u]*196 + pr[u]*4] = pf[u];
    __syncthreads();
    if (cc < 7){
      #pragma unroll
      for (int u = 0; u < 6; u++) pf[u] = xg4[pm[u]*384 + (cc+1)*48 + pr[u]];
    }
    for (int c8 = 0; c8 < 8; c8++){
      float xv[24];
      #pragma unroll
      for (int q = 0; q < 6; q++) *(f32x4*)&xv[q*4] = *(const f32x4*)&xs[mi*196 + c8*24 + q*4];
      int cg = cc*8 + c8;
      float t0 = ths[0*512 + cg*8 + oi];
      float t1 = ths[1*512 + cg*8 + oi];
      float t2 = ths[2*512 + cg*8 + oi];
      #pragma unroll
      for (int t = 0; t < 24; t++){
        acc0[t] = fmaf(t0, xv[t], acc0[t]);
        acc1[t] = fmaf(t1, xv[t], acc1[t]);
        acc2[t] = fmaf(t2, xv[t], acc2[t]);
      }
    }
  }

  #pragma unroll
  for (int k = 0; k < 3; k++){
    const float* a = (k==0) ? acc0 : (k==1) ? acc1 : acc2;
    __syncthreads();
    #pragma unroll
    for (int t = 0; t < 24; t++){
      int row = oi*24 + t;
      int sw  = (row >> 3) & 3;
      int sc  = (mi >> 3) ^ sw;
      ytile[row*32 + sc*8 + (mi & 7)] = f2bf(a[t]);
    }
    __syncthreads();
    for (int r = 0; r < 3; r++){
      int i   = tid + r*256;
      int row = i >> 2, c4 = i & 3;
      int sw  = (row >> 3) & 3;
      uint4 v = *(const uint4*)&ytile[row*32 + (c4 ^ sw)*8];
      size_t ob = ((size_t)bb*JJ + (size_t)jb*192 + row)*PP + k*NN + ms*32 + c4*8;
      *(uint4*)(Yt + ob) = v;
    }
  }
}

// ---------------- K2: per-b GEMM, 256x256x64 counted-vmcnt schedule ----------------
// stage macros: one (operand, kk-half) of K-tile t1 = 256 rows x 32 bf16 = 2 gload issues.
#define STG_A(kkv, t1) { \
    unsigned so = (unsigned)((t1)*128 + (kkv)*64); \
    unsigned ld = (unsigned)((((t1)&1)*32768) + (kkv)*16384) + wbase; \
    __builtin_amdgcn_global_load_lds((gas_cuintp)(pA + aoff0 + so), (las_uintp)(ldsA + ld), 16, 0, 0); \
    __builtin_amdgcn_global_load_lds((gas_cuintp)(pA + aoff1 + so), (las_uintp)(ldsA + ld + 8192), 16, 0, 0); }
#define STG_Y(kkv, t1) { \
    unsigned so = (unsigned)((t1)*128 + (kkv)*64); \
    unsigned ld = (unsigned)((((t1)&1)*32768) + (kkv)*16384) + wbase; \
    __builtin_amdgcn_global_load_lds((gas_cuintp)(pY + yoff0 + so), (las_uintp)(ldsY + ld), 16, 0, 0); \
    __builtin_amdgcn_global_load_lds((gas_cuintp)(pY + yoff1 + so), (las_uintp)(ldsY + ld + 8192), 16, 0, 0); }
#define FENCE_BAR  { __builtin_amdgcn_sched_barrier(0); __builtin_amdgcn_s_barrier(); }
#define LGKM_WAIT  { asm volatile("s_waitcnt lgkmcnt(0)" ::: "memory"); __builtin_amdgcn_sched_barrier(0); }

__global__ __launch_bounds__(512, 2) void kgemm(
    const unsigned short* __restrict__ Ah,
    const unsigned short* __restrict__ Yh,
    float* __restrict__ out, int b0){
  __shared__ unsigned short AsL[32768];   // [buf2][kk2][256 rows][32 bf16] = 64 KiB
  __shared__ unsigned short YsL[32768];   // 64 KiB
  int orig = blockIdx.x;
  int cpx  = (int)(gridDim.x >> 3);                // grid = NB*24, % 8 == 0 -> bijective
  int wgid = ((orig & 7) * cpx) + (orig >> 3);     // XCD swizzle
  int bb  = wgid / 24;
  int r24 = wgid - bb*24;
  int nt  = r24 / 6;                               // 4 n-tiles of 256
  int jt  = r24 - nt*6;                            // 6 j-tiles of 256
  int tid = threadIdx.x;
  int lane = tid & 63, wave = tid >> 6;
  int wr = wave >> 2, wc = wave & 3;               // 2M x 4N waves, wave tile 128x64

  // staging source byte offsets: chunk ch = i*512 + tid -> row = ch>>2, c = ch&3
  int r0 = tid >> 2, c0 = tid & 3;
  unsigned aoff0 = (unsigned)((bb*NN + nt*256 + r0) * (PP*2)) + (unsigned)(c0*16);
  unsigned aoff1 = aoff0 + (unsigned)(128 * PP * 2);
  unsigned yoff0 = (unsigned)((bb*JJ + jt*256 + r0) * (PP*2)) + (unsigned)(c0*16);
  unsigned yoff1 = yoff0 + (unsigned)(128 * PP * 2);
  const char* pA = (const char*)Ah;
  const char* pY = (const char*)Yh;
  char* ldsA = (char*)AsL;
  char* ldsY = (char*)YsL;
  unsigned wbase = (unsigned)(wave * 1024);        // wave-uniform dest; HW adds lane*16

  // ds_read thread-const offsets (in shorts): row*32 + (lane>>4)*8
  int athr = (wr*128 + (lane & 15))*32 + (lane >> 4)*8;
  int ythr = (wc*64  + (lane & 15))*32 + (lane >> 4)*8;

  f32x4 acc[8][4];
  #pragma unroll
  for (int m = 0; m < 8; m++)
    #pragma unroll
    for (int q = 0; q < 4; q++) acc[m][q] = (f32x4){0.f, 0.f, 0.f, 0.f};

  bf16x8 af[4], yf[4];

  // ---- prologue: stage tile 0 (A-kk0, Y-kk0, A-kk1, Y-kk1 = 8 loads), wait oldest 4 ----
  STG_A(0, 0); STG_Y(0, 0); STG_A(1, 0); STG_Y(1, 0);
  asm volatile("s_waitcnt vmcnt(4)" ::: "memory");
  __builtin_amdgcn_s_barrier();

  // ---- main loop: compute tile t, stage tile t+1 (1 half per phase) ----
  for (int t = 0; t < PP/64 - 1; t++){
    int cur = (t & 1) * 16384;                     // short index of current buffer
    // P1: kk0, m-half 0  (8 ds_read)
    #pragma unroll
    for (int i = 0; i < 4; i++){
      af[i] = *(const bf16x8*)&AsL[cur + i*512 + athr];
      yf[i] = *(const bf16x8*)&YsL[cur + i*512 + ythr];
    }
    STG_A(0, t+1);
    FENCE_BAR; LGKM_WAIT;
    __builtin_amdgcn_s_setprio(1);
    #pragma unroll
    for (int m = 0; m < 4; m++)
      #pragma unroll
      for (int q = 0; q < 4; q++)
        acc[m][q] = __builtin_amdgcn_mfma_f32_16x16x32_bf16(af[m], yf[q], acc[m][q], 0, 0, 0);
    __builtin_amdgcn_s_setprio(0);
    FENCE_BAR;
    // P2: kk0, m-half 1  (4 ds_read)
    #pragma unroll
    for (int i = 0; i < 4; i++)
      af[i] = *(const bf16x8*)&AsL[cur + 2048 + i*512 + athr];
    STG_Y(0, t+1);
    FENCE_BAR; LGKM_WAIT;
    __builtin_amdgcn_s_setprio(1);
    #pragma unroll
    for (int m = 0; m < 4; m++)
      #pragma unroll
      for (int q = 0; q < 4; q++)
        acc[4+m][q] = __builtin_amdgcn_mfma_f32_16x16x32_bf16(af[m], yf[q], acc[4+m][q], 0, 0, 0);
    __builtin_amdgcn_s_setprio(0);
    asm volatile("s_waitcnt vmcnt(4)" ::: "memory");   // tile t kk1 halves landed
    FENCE_BAR;
    // P3: kk1, m-half 0  (8 ds_read)
    #pragma unroll
    for (int i = 0; i < 4; i++){
      af[i] = *(const bf16x8*)&AsL[cur + 8192 + i*512 + athr];
      yf[i] = *(const bf16x8*)&YsL[cur + 8192 + i*512 + ythr];
    }
    STG_A(1, t+1);
    FENCE_BAR; LGKM_WAIT;
    __builtin_amdgcn_s_setprio(1);
    #pragma unroll
    for (int m = 0; m < 4; m++)
      #pragma unroll
      for (int q = 0; q < 4; q++)
        acc[m][q] = __builtin_amdgcn_mfma_f32_16x16x32_bf16(af[m], yf[q], acc[m][q], 0, 0, 0);
    __builtin_amdgcn_s_setprio(0);
    FENCE_BAR;
    // P4: kk1, m-half 1  (4 ds_read)
    #pragma unroll
    for (int i = 0; i < 4; i++)
      af[i] = *(const bf16x8*)&AsL[cur + 8192 + 2048 + i*512 + athr];
    STG_Y(1, t+1);
    FENCE_BAR; LGKM_WAIT;
    __builtin_amdgcn_s_setprio(1);
    #pragma unroll
    for (int m = 0; m < 4; m++)
      #pragma unroll
      for (int q = 0; q < 4; q++)
        acc[4+m][q] = __builtin_amdgcn_mfma_f32_16x16x32_bf16(af[m], yf[q], acc[4+m][q], 0, 0, 0);
    __builtin_amdgcn_s_setprio(0);
    asm volatile("s_waitcnt vmcnt(4)" ::: "memory");   // tile t+1 kk0 halves landed
    FENCE_BAR;
  }

  // ---- tail tile t = 47 (no staging; drain before kk1) ----
  {
    int cur = ((PP/64 - 1) & 1) * 16384;
    #pragma unroll
    for (int i = 0; i < 4; i++){
      af[i] = *(const bf16x8*)&AsL[cur + i*512 + athr];
      yf[i] = *(const bf16x8*)&YsL[cur + i*512 + ythr];
    }
    FENCE_BAR; LGKM_WAIT;
    #pragma unroll
    for (int m = 0; m < 4; m++)
      #pragma unroll
      for (int q = 0; q < 4; q++)
        acc[m][q] = __builtin_amdgcn_mfma_f32_16x16x32_bf16(af[m], yf[q], acc[m][q], 0, 0, 0);
    FENCE_BAR;
    #pragma unroll
    for (int i = 0; i < 4; i++)
      af[i] = *(const bf16x8*)&AsL[cur + 2048 + i*512 + athr];
    FENCE_BAR; LGKM_WAIT;
    #pragma unroll
    for (int m = 0; m < 4; m++)
      #pragma unroll
      for (int q = 0; q < 4; q++)
        acc[4+m][q] = __builtin_amdgcn_mfma_f32_16x16x32_bf16(af[m], yf[q], acc[4+m][q], 0, 0, 0);
    asm volatile("s_waitcnt vmcnt(0)" ::: "memory");   // kk1 halves landed (epilogue drain)
    FENCE_BAR;
    #pragma unroll
    for (int i = 0; i < 4; i++){
      af[i] = *(const bf16x8*)&AsL[cur + 8192 + i*512 + athr];
      yf[i] = *(const bf16x8*)&YsL[cur + 8192 + i*512 + ythr];
    }
    FENCE_BAR; LGKM_WAIT;
    #pragma unroll
    for (int m = 0; m < 4; m++)
      #pragma unroll
      for (int q = 0; q < 4; q++)
        acc[m][q] = __builtin_amdgcn_mfma_f32_16x16x32_bf16(af[m], yf[q], acc[m][q], 0, 0, 0);
    FENCE_BAR;
    #pragma unroll
    for (int i = 0; i < 4; i++)
      af[i] = *(const bf16x8*)&AsL[cur + 8192 + 2048 + i*512 + athr];
    LGKM_WAIT;
    #pragma unroll
    for (int m = 0; m < 4; m++)
      #pragma unroll
      for (int q = 0; q < 4; q++)
        acc[4+m][q] = __builtin_amdgcn_mfma_f32_16x16x32_bf16(af[m], yf[q], acc[4+m][q], 0, 0, 0);
  }

  // ---- epilogue: relu + store (C/D: col=lane&15 -> j, row=(lane>>4)*4+e -> n) ----
  size_t ob = (size_t)(b0 + bb) * NN * JJ;
  int jbase = jt*256 + wc*64 + (lane & 15);
  int nbase = nt*256 + wr*128 + ((lane >> 4) << 2);
  #pragma unroll
  for (int m = 0; m < 8; m++){
    #pragma unroll
    for (int q = 0; q < 4; q++){
      int j = jbase + q*16;
      #pragma unroll
      for (int e = 0; e < 4; e++){
        float v = acc[m][q][e];
        v = v > 0.f ? v : 0.f;
        out[ob + (size_t)(nbase + m*16 + e) * JJ + j] = v;
      }
    }
  }
}

extern "C" void kernel_launch(void* const* d_in, const int* in_sizes, int n_in,
                              void* d_out, int out_size, void* d_ws, size_t ws_size,
                              hipStream_t stream){
  (void)in_sizes; (void)n_in; (void)out_size;
  const float* x     = (const float*)d_in[0];   // [16][1024][64][24]
  const float* stdg  = (const float*)d_in[1];   // [16][1024][1024]
  const float* cheb  = (const float*)d_in[2];   // [3][1024][1024]
  const float* theta = (const float*)d_in[3];   // [3][64][64]
  float* out = (float*)d_out;                   // [16][1024][64][24] viewed as [16][1024][1536]

  const size_t szA_b = (size_t)NN * PP * sizeof(unsigned short);  // 6.29 MB
  const size_t szY_b = (size_t)PP * JJ * sizeof(unsigned short);  // 9.44 MB
  const size_t per_b = szA_b + szY_b;                             // 15.73 MB
  int NB = 16;
  while (NB > 1 && per_b * (size_t)NB > ws_size) NB >>= 1;        // NB in {16,8,4,2,1}

  char* w = (char*)d_ws;
  unsigned short* Ah = (unsigned short*)w;                         w += szA_b * NB;  // [bb][n][p]
  unsigned short* Yt = (unsigned short*)w;                         w += szY_b * NB;  // [bb][j][p]

  for (int b0 = 0; b0 < BB; b0 += NB){
    kprepA<<<dim3(16, 16),    256, 0, stream>>>(cheb, stdg, Ah, b0, NB);
    kprepY<<<dim3(32, 8, NB), 256, 0, stream>>>(x, theta, Yt, b0);
    kgemm<<<dim3(NB*24),      512, 0, stream>>>(Ah, Yt, out, b0);
  }
}